// Round 1
// baseline (664.453 us; speedup 1.0000x reference)
//
#include <hip/hip_runtime.h>
#include <hip/hip_bf16.h>
#include <math.h>

typedef __bf16 bf16x8 __attribute__((ext_vector_type(8)));
typedef float  f32x4  __attribute__((ext_vector_type(4)));
typedef unsigned int   u32;
typedef unsigned short u16;
typedef u16 u16x8 __attribute__((ext_vector_type(8)));

#define D_   1024
#define M_   8192

// ---------- helpers ----------
static __device__ __forceinline__ u16 f2bf(float f) {            // RNE float->bf16
  u32 x = __float_as_uint(f);
  u32 r = (x + 0x7fffu + ((x >> 16) & 1u)) >> 16;
  return (u16)r;
}
static __device__ __forceinline__ float bf2f(u16 s) {
  union { u32 b; float f; } u; u.b = ((u32)s) << 16; return u.f;
}
static __device__ __forceinline__ void gload16(const u16* g, u16* l) {
  __builtin_amdgcn_global_load_lds((const __attribute__((address_space(1))) u32*)g,
                                   (__attribute__((address_space(3))) u32*)l, 16, 0, 0);
}

// ---------- pack kernels (tile-staged blob layout: [..][kblk][kb(4)][128][8]) ----------

// x -> bf16x2 A-pack for memory layers. dst [64 mblk][64 kblk][512][8]
// kblk<32: hi(k=kblk*32+kb*8+j) ; kblk>=32: lo(k=(kblk-32)*32+kb*8+j)
__global__ __launch_bounds__(256) void pack_A_mem(const float* __restrict__ x, u16* __restrict__ dst) {
  int gid = blockIdx.x * 256 + threadIdx.x;            // 64*64*512 = 2,097,152 chunks
  int u    = gid & 511;
  int kblk = (gid >> 9) & 63;
  int mblk = gid >> 15;
  int kb = u >> 7, r = u & 127;
  int m  = mblk * 128 + r;
  int lo = kblk >> 5;
  int k0 = (kblk & 31) * 32 + kb * 8;
  const float* src = x + (size_t)m * D_ + k0;
  u16x8 out;
#pragma unroll
  for (int j = 0; j < 8; ++j) {
    float v = src[j];
    u16 h = f2bf(v);
    out[j] = lo ? f2bf(v - bf2f(h)) : h;
  }
  *reinterpret_cast<u16x8*>(dst + (size_t)gid * 8) = out;
}

// Wm (2 layers) -> bf16x2 B-pack. dst [c(2)][8 nblk][64 kblk][512][8]
__global__ __launch_bounds__(256) void pack_W_mem(const float* __restrict__ W, u16* __restrict__ dst) {
  int gid = blockIdx.x * 256 + threadIdx.x;            // 2*8*64*512 = 524,288
  int u    = gid & 511;
  int kblk = (gid >> 9) & 63;
  int nblk = (gid >> 15) & 7;
  int c    = gid >> 18;
  int kb = u >> 7, col = u & 127;
  int n  = nblk * 128 + col;
  int lo = kblk >> 5;
  int k0 = (kblk & 31) * 32 + kb * 8;
  const float* src = W + (size_t)c * D_ * D_ + (size_t)k0 * D_ + n;
  u16x8 out;
#pragma unroll
  for (int j = 0; j < 8; ++j) {
    float v = src[(size_t)j * D_];
    u16 h = f2bf(v);
    out[j] = lo ? f2bf(v - bf2f(h)) : h;
  }
  *reinterpret_cast<u16x8*>(dst + (size_t)gid * 8) = out;
}

// x -> plain bf16 A-pack (K=1024). dst [64 mblk][32 kblk][512][8]
__global__ __launch_bounds__(256) void pack_A_plain(const float* __restrict__ x, u16* __restrict__ dst) {
  int gid = blockIdx.x * 256 + threadIdx.x;            // 64*32*512 = 1,048,576
  int u    = gid & 511;
  int kblk = (gid >> 9) & 31;
  int mblk = gid >> 14;
  int kb = u >> 7, r = u & 127;
  int m  = mblk * 128 + r;
  int k0 = kblk * 32 + kb * 8;
  const float* src = x + (size_t)m * D_ + k0;
  u16x8 out;
#pragma unroll
  for (int j = 0; j < 8; ++j) out[j] = f2bf(src[j]);
  *reinterpret_cast<u16x8*>(dst + (size_t)gid * 8) = out;
}

// generic plain bf16 B-pack for E stacked [K x 1024] matrices (K = KBLK*32).
// dst [e][8 nblk][KBLK][512][8]
__global__ __launch_bounds__(256) void pack_W_plain(const float* __restrict__ W, u16* __restrict__ dst, int KBLK) {
  int gid = blockIdx.x * 256 + threadIdx.x;
  int u    = gid & 511;
  int t    = gid >> 9;
  int kblk = t % KBLK;
  int rest = t / KBLK;
  int nblk = rest & 7;
  int e    = rest >> 3;
  int kb = u >> 7, col = u & 127;
  int n  = nblk * 128 + col;
  int k0 = kblk * 32 + kb * 8;
  const float* src = W + ((size_t)e * KBLK * 32 + k0) * D_ + n;
  u16x8 out;
#pragma unroll
  for (int j = 0; j < 8; ++j) out[j] = f2bf(src[(size_t)j * D_]);
  *reinterpret_cast<u16x8*>(dst + (size_t)gid * 8) = out;
}

// [link bf16 [M][2048] | x f32 [M][1024]] -> Hpack [64 mblk][96 kblk][512][8]
__global__ __launch_bounds__(256) void pack_H(const u16* __restrict__ link, const float* __restrict__ x,
                                              u16* __restrict__ dst) {
  int gid = blockIdx.x * 256 + threadIdx.x;            // 64*96*512 = 3,145,728
  int u    = gid & 511;
  int t    = gid >> 9;
  int kblk = t % 96;
  int mblk = t / 96;
  int kb = u >> 7, r = u & 127;
  int m  = mblk * 128 + r;
  int k0 = kblk * 32 + kb * 8;
  u16x8 out;
  if (k0 < 2048) {
    out = *reinterpret_cast<const u16x8*>(link + (size_t)m * 2048 + k0);
  } else {
    const float* src = x + (size_t)m * D_ + (k0 - 2048);
#pragma unroll
    for (int j = 0; j < 8; ++j) out[j] = f2bf(src[j]);
  }
  *reinterpret_cast<u16x8*>(dst + (size_t)gid * 8) = out;
}

// ---------- LN kernels ----------
__global__ __launch_bounds__(256) void ln_residual(const float* __restrict__ xin, const float* __restrict__ mem,
                                                   const float* __restrict__ bias, const float* __restrict__ g,
                                                   const float* __restrict__ b, float* __restrict__ xout) {
  int row = blockIdx.x, tid = threadIdx.x;
  const f32x4 mv = *reinterpret_cast<const f32x4*>(mem + (size_t)row * D_ + tid * 4);
  const f32x4 bi = *reinterpret_cast<const f32x4*>(bias + tid * 4);
  float a[4]; float s = 0.f, ss = 0.f;
#pragma unroll
  for (int i = 0; i < 4; ++i) { a[i] = mv[i] + bi[i]; s += a[i]; ss += a[i] * a[i]; }
#pragma unroll
  for (int o = 1; o < 64; o <<= 1) { s += __shfl_xor(s, o); ss += __shfl_xor(ss, o); }
  __shared__ float red[8];
  int wv = tid >> 6, ln = tid & 63;
  if (ln == 0) { red[wv] = s; red[4 + wv] = ss; }
  __syncthreads();
  float S  = red[0] + red[1] + red[2] + red[3];
  float SS = red[4] + red[5] + red[6] + red[7];
  float mean = S * (1.f / 1024.f);
  float var  = SS * (1.f / 1024.f) - mean * mean;
  float rs = rsqrtf(var + 1e-5f);
  const f32x4 g4 = *reinterpret_cast<const f32x4*>(g + tid * 4);
  const f32x4 b4 = *reinterpret_cast<const f32x4*>(b + tid * 4);
  const f32x4 xv = *reinterpret_cast<const f32x4*>(xin + (size_t)row * D_ + tid * 4);
  f32x4 o4;
#pragma unroll
  for (int i = 0; i < 4; ++i) o4[i] = xv[i] + (a[i] - mean) * rs * g4[i] + b4[i];
  *reinterpret_cast<f32x4*>(xout + (size_t)row * D_ + tid * 4) = o4;
}

__global__ __launch_bounds__(256) void final_ln_gelu(const float* __restrict__ fit, const float* __restrict__ bfit,
                                                     const float* __restrict__ g, const float* __restrict__ b,
                                                     float* __restrict__ out) {
  int row = blockIdx.x, tid = threadIdx.x;
  const f32x4 hv = *reinterpret_cast<const f32x4*>(fit + (size_t)row * D_ + tid * 4);
  const f32x4 bi = *reinterpret_cast<const f32x4*>(bfit + tid * 4);
  float a[4]; float s = 0.f, ss = 0.f;
#pragma unroll
  for (int i = 0; i < 4; ++i) { a[i] = hv[i] + bi[i]; s += a[i]; ss += a[i] * a[i]; }
#pragma unroll
  for (int o = 1; o < 64; o <<= 1) { s += __shfl_xor(s, o); ss += __shfl_xor(ss, o); }
  __shared__ float red[8];
  int wv = tid >> 6, ln = tid & 63;
  if (ln == 0) { red[wv] = s; red[4 + wv] = ss; }
  __syncthreads();
  float S  = red[0] + red[1] + red[2] + red[3];
  float SS = red[4] + red[5] + red[6] + red[7];
  float mean = S * (1.f / 1024.f);
  float var  = SS * (1.f / 1024.f) - mean * mean;
  float rs = rsqrtf(var + 1e-5f);
  const f32x4 g4 = *reinterpret_cast<const f32x4*>(g + tid * 4);
  const f32x4 b4 = *reinterpret_cast<const f32x4*>(b + tid * 4);
  f32x4 o4;
#pragma unroll
  for (int i = 0; i < 4; ++i) {
    float y = (a[i] - mean) * rs * g4[i] + b4[i];
    o4[i] = 0.5f * y * (1.f + erff(y * 0.70710678118654752f));
  }
  *reinterpret_cast<f32x4*>(out + (size_t)row * D_ + tid * 4) = o4;
}

// ---------- gate + top-2 ----------
__global__ __launch_bounds__(256) void gate_topk(const float* __restrict__ x, const float* __restrict__ Wg,
                                                 const float* __restrict__ bg, int2* __restrict__ idx) {
  int tid = threadIdx.x;
  int token = blockIdx.x * 4 + (tid >> 6);
  int ln = tid & 63;
  const float* xr = x + (size_t)token * D_;
  float a0 = 0.f, a1 = 0.f, a2 = 0.f, a3 = 0.f;
  for (int d = ln; d < D_; d += 64) {
    float xv = xr[d];
    const f32x4 w = *reinterpret_cast<const f32x4*>(Wg + (size_t)d * 4);
    a0 += xv * w[0]; a1 += xv * w[1]; a2 += xv * w[2]; a3 += xv * w[3];
  }
#pragma unroll
  for (int o = 1; o < 64; o <<= 1) {
    a0 += __shfl_xor(a0, o); a1 += __shfl_xor(a1, o);
    a2 += __shfl_xor(a2, o); a3 += __shfl_xor(a3, o);
  }
  if (ln == 0) {
    float lg[4] = { a0 + bg[0], a1 + bg[1], a2 + bg[2], a3 + bg[3] };
    int i0 = 0; float v0 = lg[0];
#pragma unroll
    for (int k = 1; k < 4; ++k) if (lg[k] > v0) { v0 = lg[k]; i0 = k; }
    int i1 = -1; float v1 = -3.4e38f;
#pragma unroll
    for (int k = 0; k < 4; ++k) if (k != i0 && lg[k] > v1) { v1 = lg[k]; i1 = k; }
    idx[token] = make_int2(i0, i1);
  }
}

// ---------- GEMM (m97-style 128x128, BK=32, gload_lds, 16x16x32 bf16 MFMA) ----------
// MEMFOLD=1: K'=3072 bf16x2 loop with A stored K=2048 (hi|lo) and B stored K=2048 (hi|lo):
//   kblk 0..31: ah*bh, 32..63: ah*bl, 64..95: al*bh
// EPI=0: C fp32 [M][1024].  EPI=1: expert-select -> link bf16 [M][2048], expert = blockIdx.z.
template<int MEMFOLD, int EPI>
__global__ __launch_bounds__(256) void gemm_kernel(const u16* __restrict__ A, const u16* __restrict__ B,
                                                   float* __restrict__ C, u16* __restrict__ link,
                                                   const int2* __restrict__ idx, const float* __restrict__ be,
                                                   int KBLK) {
  __shared__ __align__(16) u16 As[4096];
  __shared__ __align__(16) u16 Bs[4096];
  const int mblk = blockIdx.x, nblk = blockIdx.y, e = blockIdx.z;
  const int tid = threadIdx.x;
  const int w = tid >> 6, l = tid & 63;
  const int wm = w >> 1, wn = w & 1;
  const int lk = l >> 4, l15 = l & 15;

  const u16* Bp = B;
  if (EPI == 1) Bp += (size_t)e * (8 * 32 * 4096);
  const int aKB = MEMFOLD ? 64 : KBLK;
  const int bKB = MEMFOLD ? 64 : KBLK;

  f32x4 acc[4][4];
#pragma unroll
  for (int i = 0; i < 4; ++i)
#pragma unroll
    for (int j = 0; j < 4; ++j) acc[i][j] = (f32x4){0.f, 0.f, 0.f, 0.f};

  for (int kblk = 0; kblk < KBLK; ++kblk) {
    int ablk = MEMFOLD ? (kblk < 32 ? kblk : kblk - 32) : kblk;
    int bblk = MEMFOLD ? (kblk < 64 ? kblk : kblk - 64) : kblk;
    const u16* Ab = A  + (size_t)(mblk * aKB + ablk) * 4096;
    const u16* Bb = Bp + (size_t)(nblk * bKB + bblk) * 4096;
#pragma unroll
    for (int i = 0; i < 2; ++i) {
      int u = i * 256 + tid;
      gload16(Ab + (size_t)u * 8, &As[u * 8]);
      gload16(Bb + (size_t)u * 8, &Bs[u * 8]);
    }
    __syncthreads();
    bf16x8 af[4], bfr[4];
#pragma unroll
    for (int mi = 0; mi < 4; ++mi)
      af[mi] = *reinterpret_cast<const bf16x8*>(&As[(lk * 128 + wm * 64 + mi * 16 + l15) * 8]);
#pragma unroll
    for (int ni = 0; ni < 4; ++ni)
      bfr[ni] = *reinterpret_cast<const bf16x8*>(&Bs[(lk * 128 + wn * 64 + ni * 16 + l15) * 8]);
#pragma unroll
    for (int mi = 0; mi < 4; ++mi)
#pragma unroll
      for (int ni = 0; ni < 4; ++ni)
        acc[mi][ni] = __builtin_amdgcn_mfma_f32_16x16x32_bf16(af[mi], bfr[ni], acc[mi][ni], 0, 0, 0);
    __syncthreads();
  }

  if (EPI == 0) {
#pragma unroll
    for (int mi = 0; mi < 4; ++mi)
#pragma unroll
      for (int jj = 0; jj < 4; ++jj) {
        int row = mblk * 128 + wm * 64 + mi * 16 + lk * 4 + jj;
#pragma unroll
        for (int ni = 0; ni < 4; ++ni) {
          int col = nblk * 128 + wn * 64 + ni * 16 + l15;
          C[(size_t)row * D_ + col] = acc[mi][ni][jj];
        }
      }
  } else {
#pragma unroll
    for (int mi = 0; mi < 4; ++mi) {
      int2 rid[4];
#pragma unroll
      for (int jj = 0; jj < 4; ++jj)
        rid[jj] = idx[mblk * 128 + wm * 64 + mi * 16 + lk * 4 + jj];
#pragma unroll
      for (int ni = 0; ni < 4; ++ni) {
        int col = nblk * 128 + wn * 64 + ni * 16 + l15;
        float bev = be[(size_t)e * D_ + col];
#pragma unroll
        for (int jj = 0; jj < 4; ++jj) {
          int slot = (rid[jj].x == e) ? 0 : ((rid[jj].y == e) ? 1 : -1);
          if (slot >= 0) {
            int row = mblk * 128 + wm * 64 + mi * 16 + lk * 4 + jj;
            link[(size_t)row * 2048 + slot * D_ + col] = f2bf(acc[mi][ni][jj] + bev);
          }
        }
      }
    }
  }
}

// ---------- launch ----------
extern "C" void kernel_launch(void* const* d_in, const int* in_sizes, int n_in,
                              void* d_out, int out_size, void* d_ws, size_t ws_size,
                              hipStream_t stream) {
  const float* x_in = (const float*)d_in[0];
  const float* Wm   = (const float*)d_in[1];
  const float* bm   = (const float*)d_in[2];
  const float* ln_g = (const float*)d_in[3];
  const float* ln_b = (const float*)d_in[4];
  const float* Wg   = (const float*)d_in[5];
  const float* bg   = (const float*)d_in[6];
  const float* We   = (const float*)d_in[7];
  const float* be   = (const float*)d_in[8];
  const float* Wfit = (const float*)d_in[9];
  const float* bfit = (const float*)d_in[10];
  float* out = (float*)d_out;

  char* ws = (char*)d_ws;
  size_t off = 0;
  auto alloc = [&](size_t bytes) -> void* {
    void* p = ws + off; off += (bytes + 255) & ~(size_t)255; return p;
  };
  float* x_cur   = (float*)alloc((size_t)M_ * D_ * 4);          // 33.5 MB
  float* memb    = (float*)alloc((size_t)M_ * D_ * 4);          // 33.5 MB (mem, later fit)
  u16*   Apack   = (u16*)alloc((size_t)64 * 96 * 4096 * 2);     // 50.3 MB (mem-A uses 64 kblk; Hpack uses 96)
  u16*   Apack2  = (u16*)alloc((size_t)64 * 32 * 4096 * 2);     // 16.8 MB
  u16*   WmPack  = (u16*)alloc((size_t)2 * 8 * 64 * 4096 * 2);  // 8.4 MB
  u16*   WePack  = (u16*)alloc((size_t)4 * 8 * 32 * 4096 * 2);  // 8.4 MB
  u16*   WfPack  = (u16*)alloc((size_t)8 * 96 * 4096 * 2);      // 6.3 MB
  u16*   linkb   = (u16*)alloc((size_t)M_ * 2048 * 2);          // 33.5 MB
  int2*  idxb    = (int2*)alloc((size_t)M_ * 8);                // 64 KB

  dim3 blk(256);
  // weight packs (independent of x pipeline)
  pack_W_mem  <<<524288 / 256, blk, 0, stream>>>(Wm, WmPack);
  pack_W_plain<<<524288 / 256, blk, 0, stream>>>(We, WePack, 32);
  pack_W_plain<<<393216 / 256, blk, 0, stream>>>(Wfit, WfPack, 96);

  // memory layer 0
  pack_A_mem<<<2097152 / 256, blk, 0, stream>>>(x_in, Apack);
  gemm_kernel<1, 0><<<dim3(64, 8, 1), blk, 0, stream>>>(Apack, WmPack, memb, nullptr, nullptr, nullptr, 96);
  ln_residual<<<M_, blk, 0, stream>>>(x_in, memb, bm, ln_g, ln_b, x_cur);
  // memory layer 1
  pack_A_mem<<<2097152 / 256, blk, 0, stream>>>(x_cur, Apack);
  gemm_kernel<1, 0><<<dim3(64, 8, 1), blk, 0, stream>>>(Apack, WmPack + (size_t)8 * 64 * 4096, memb,
                                                        nullptr, nullptr, nullptr, 96);
  ln_residual<<<M_, blk, 0, stream>>>(x_cur, memb, bm + D_, ln_g, ln_b, x_cur);

  // gate + top-2
  gate_topk<<<M_ / 4, blk, 0, stream>>>(x_cur, Wg, bg, idxb);

  // experts with fused selection -> link (bf16)
  pack_A_plain<<<1048576 / 256, blk, 0, stream>>>(x_cur, Apack2);
  gemm_kernel<0, 1><<<dim3(64, 8, 4), blk, 0, stream>>>(Apack2, WePack, nullptr, linkb, idxb, be, 32);

  // fit: h = [link | x] @ Wfit
  pack_H<<<3145728 / 256, blk, 0, stream>>>(linkb, x_cur, Apack);
  gemm_kernel<0, 0><<<dim3(64, 8, 1), blk, 0, stream>>>(Apack, WfPack, memb, nullptr, nullptr, nullptr, 96);

  // final LN + exact GELU
  final_ln_gelu<<<M_, blk, 0, stream>>>(memb, bfit, ln_g, ln_b, out);
}

// Round 2
// 491.265 us; speedup vs baseline: 1.3525x; 1.3525x over previous
//
#include <hip/hip_runtime.h>
#include <hip/hip_bf16.h>
#include <math.h>

typedef __bf16 bf16x8 __attribute__((ext_vector_type(8)));
typedef float  f32x4  __attribute__((ext_vector_type(4)));
typedef unsigned int   u32;
typedef unsigned short u16;
typedef u16 u16x8 __attribute__((ext_vector_type(8)));

#define D_ 1024
#define M_ 8192

static __device__ __forceinline__ u16 f2bf(float f) {            // RNE float->bf16
  u32 x = __float_as_uint(f);
  return (u16)((x + 0x7fffu + ((x >> 16) & 1u)) >> 16);
}
static __device__ __forceinline__ float bf2f(u16 s) {
  union { u32 b; float f; } u; u.b = ((u32)s) << 16; return u.f;
}
static __device__ __forceinline__ void gload16(const u16* g, u16* l) {
  __builtin_amdgcn_global_load_lds((const __attribute__((address_space(1))) u32*)g,
                                   (__attribute__((address_space(3))) u32*)l, 16, 0, 0);
}

// ============================================================================
// Pack layouts (all 16B granules of 8 bf16, XOR-swizzled for conflict-free
// ds_read_b128):  A-blobs  [mblk][kblk64][2048 gran]  (256 rows x 8 kg)
//                 B-blobs  [e][nblk][kblk64][1024 gran](128 cols x 8 kg)
// granule slot (row, gp) holds data k-granule kg = gp ^ (row & 7).
// ============================================================================

// x (f32 [8192][1024]) -> bf16x2 A-pack [32 mblk][32 kblk][2048]  (hi: kblk<16, lo: >=16)
__global__ __launch_bounds__(256) void pack_A_mem(const float* __restrict__ x, u16* __restrict__ dst) {
  int gid = blockIdx.x * 256 + threadIdx.x;           // 2,097,152 granules
  int G = gid & 2047;
  int kblk = (gid >> 11) & 31;
  int mblk = gid >> 16;
  int rrow = G >> 3, gp = G & 7;
  int kg = gp ^ (rrow & 7);
  int region = kblk >> 4;                              // 0 hi, 1 lo
  int k = ((kblk & 15) * 8 + kg) * 8;
  const float* src = x + ((size_t)mblk * 256 + rrow) * D_ + k;
  f32x4 v0 = *reinterpret_cast<const f32x4*>(src);
  f32x4 v1 = *reinterpret_cast<const f32x4*>(src + 4);
  u16x8 o8;
#pragma unroll
  for (int j = 0; j < 4; ++j) {
    u16 h0 = f2bf(v0[j]); o8[j]     = region ? f2bf(v0[j] - bf2f(h0)) : h0;
    u16 h1 = f2bf(v1[j]); o8[4 + j] = region ? f2bf(v1[j] - bf2f(h1)) : h1;
  }
  *reinterpret_cast<u16x8*>(dst + (size_t)gid * 8) = o8;
}

// Wm f32 [2][1024][1024] -> WmPack [c][8 nblk][32 kblk][1024]  (hi kblk<16 | lo)
// grid 256 blocks (c*128 + kt*8 + nt), LDS-tiled transpose.
__global__ __launch_bounds__(256) void pack_W_mem(const float* __restrict__ W, u16* __restrict__ dst) {
  __shared__ float tile[64][129];
  int bidx = blockIdx.x;
  int nt = bidx & 7, kt = (bidx >> 3) & 15, c = bidx >> 7;
  const float* Ws = W + ((size_t)c * D_ + kt * 64) * D_ + nt * 128;
#pragma unroll
  for (int rep = 0; rep < 32; ++rep) {
    int idx = rep * 256 + threadIdx.x;
    tile[idx >> 7][idx & 127] = Ws[(size_t)(idx >> 7) * D_ + (idx & 127)];
  }
  __syncthreads();
#pragma unroll
  for (int rep = 0; rep < 8; ++rep) {
    int gi = rep * 256 + threadIdx.x;                  // 0..2047 (hi + lo)
    int region = gi >> 10;
    int G = gi & 1023;
    int col = G >> 3, gp = G & 7;
    int kg = gp ^ (col & 7);
    u16x8 o8;
#pragma unroll
    for (int j = 0; j < 8; ++j) {
      float v = tile[kg * 8 + j][col];
      u16 h = f2bf(v);
      o8[j] = region ? f2bf(v - bf2f(h)) : h;
    }
    int kblk = region * 16 + kt;
    size_t off = ((((size_t)c * 8 + nt) * 32 + kblk) * 1024 + col * 8 + gp) * 8;
    *reinterpret_cast<u16x8*>(dst + off) = o8;
  }
}

// W f32 (E slabs of [KBLK*64][1024]) -> [e][8 nblk][KBLK][1024], plain bf16.
// grid E*KBLK*8 blocks: b = (e*KBLK + kt)*8 + nt
__global__ __launch_bounds__(256) void pack_W_plain(const float* __restrict__ W, u16* __restrict__ dst, int KBLK) {
  __shared__ float tile[64][129];
  int bidx = blockIdx.x;
  int nt = bidx & 7;
  int t2 = bidx >> 3;
  int kt = t2 % KBLK;
  int e  = t2 / KBLK;
  const float* Ws = W + ((size_t)e * KBLK * 64 + kt * 64) * D_ + nt * 128;
#pragma unroll
  for (int rep = 0; rep < 32; ++rep) {
    int idx = rep * 256 + threadIdx.x;
    tile[idx >> 7][idx & 127] = Ws[(size_t)(idx >> 7) * D_ + (idx & 127)];
  }
  __syncthreads();
#pragma unroll
  for (int rep = 0; rep < 4; ++rep) {
    int gi = rep * 256 + threadIdx.x;                  // 0..1023
    int col = gi >> 3, gp = gi & 7;
    int kg = gp ^ (col & 7);
    u16x8 o8;
#pragma unroll
    for (int j = 0; j < 8; ++j) o8[j] = f2bf(tile[kg * 8 + j][col]);
    size_t off = ((((size_t)e * 8 + nt) * KBLK + kt) * 1024 + col * 8 + gp) * 8;
    *reinterpret_cast<u16x8*>(dst + off) = o8;
  }
}

// ============================================================================
// Fused LN kernels (1 row per 256-thread block)
// ============================================================================

// layer-1: x1 = x + LN(mem+bm); write x1 f32 AND bf16x2 A-pack for layer-2 GEMM
__global__ __launch_bounds__(256) void ln1_pack(const float* __restrict__ xin, const float* __restrict__ mem,
                                                const float* __restrict__ bm, const float* __restrict__ g,
                                                const float* __restrict__ b, float* __restrict__ xout,
                                                u16* __restrict__ apack) {
  int row = blockIdx.x, tid = threadIdx.x;
  __shared__ float yrow[1024];
  __shared__ float red[8];
  f32x4 mv = *reinterpret_cast<const f32x4*>(mem + (size_t)row * D_ + tid * 4);
  f32x4 bi = *reinterpret_cast<const f32x4*>(bm + tid * 4);
  float a[4]; float s = 0.f, ss = 0.f;
#pragma unroll
  for (int i = 0; i < 4; ++i) { a[i] = mv[i] + bi[i]; s += a[i]; ss += a[i] * a[i]; }
#pragma unroll
  for (int o = 1; o < 64; o <<= 1) { s += __shfl_xor(s, o); ss += __shfl_xor(ss, o); }
  int wv = tid >> 6, ln = tid & 63;
  if (ln == 0) { red[wv] = s; red[4 + wv] = ss; }
  __syncthreads();
  float S = red[0] + red[1] + red[2] + red[3];
  float SS = red[4] + red[5] + red[6] + red[7];
  float mean = S * (1.f / 1024.f);
  float var = SS * (1.f / 1024.f) - mean * mean;
  float rs = rsqrtf(var + 1e-5f);
  f32x4 g4 = *reinterpret_cast<const f32x4*>(g + tid * 4);
  f32x4 b4 = *reinterpret_cast<const f32x4*>(b + tid * 4);
  f32x4 xv = *reinterpret_cast<const f32x4*>(xin + (size_t)row * D_ + tid * 4);
  f32x4 o4;
#pragma unroll
  for (int i = 0; i < 4; ++i) o4[i] = xv[i] + (a[i] - mean) * rs * g4[i] + b4[i];
  *reinterpret_cast<f32x4*>(xout + (size_t)row * D_ + tid * 4) = o4;
  *reinterpret_cast<f32x4*>(yrow + tid * 4) = o4;
  __syncthreads();
  // pack: thread = one granule (hi for tid<128, lo else)
  int region = tid >> 7;
  int q = tid & 127;                                   // data granule 0..127
  int kblk = region * 16 + (q >> 3);
  int kg = q & 7;
  int rrow = row & 255, mblk = row >> 8;
  const float* ys = yrow + q * 8;
  u16x8 o8;
#pragma unroll
  for (int j = 0; j < 8; ++j) {
    float v = ys[j]; u16 h = f2bf(v);
    o8[j] = region ? f2bf(v - bf2f(h)) : h;
  }
  size_t off = (((size_t)mblk * 32 + kblk) * 2048 + rrow * 8 + (kg ^ (rrow & 7))) * 8;
  *reinterpret_cast<u16x8*>(apack + off) = o8;
}

// layer-2: x2 = x1 + LN(mem+bm1); fused gate top-2; write expert A-pack (plain bf16)
// and the x-section (kblk 32..47) of the fit H-pack.
__global__ __launch_bounds__(256) void ln2_gate_pack(const float* __restrict__ xin, const float* __restrict__ mem,
                                                     const float* __restrict__ bm1, const float* __restrict__ g,
                                                     const float* __restrict__ b, const float* __restrict__ Wg,
                                                     const float* __restrict__ bg, u16* __restrict__ apack,
                                                     u16* __restrict__ hpack, int2* __restrict__ idx) {
  int row = blockIdx.x, tid = threadIdx.x;
  __shared__ float yrow[1024];
  __shared__ float red[8];
  __shared__ float gred[16];
  f32x4 mv = *reinterpret_cast<const f32x4*>(mem + (size_t)row * D_ + tid * 4);
  f32x4 bi = *reinterpret_cast<const f32x4*>(bm1 + tid * 4);
  float a[4]; float s = 0.f, ss = 0.f;
#pragma unroll
  for (int i = 0; i < 4; ++i) { a[i] = mv[i] + bi[i]; s += a[i]; ss += a[i] * a[i]; }
#pragma unroll
  for (int o = 1; o < 64; o <<= 1) { s += __shfl_xor(s, o); ss += __shfl_xor(ss, o); }
  int wv = tid >> 6, ln = tid & 63;
  if (ln == 0) { red[wv] = s; red[4 + wv] = ss; }
  __syncthreads();
  float S = red[0] + red[1] + red[2] + red[3];
  float SS = red[4] + red[5] + red[6] + red[7];
  float mean = S * (1.f / 1024.f);
  float var = SS * (1.f / 1024.f) - mean * mean;
  float rs = rsqrtf(var + 1e-5f);
  f32x4 g4 = *reinterpret_cast<const f32x4*>(g + tid * 4);
  f32x4 b4 = *reinterpret_cast<const f32x4*>(b + tid * 4);
  f32x4 xv = *reinterpret_cast<const f32x4*>(xin + (size_t)row * D_ + tid * 4);
  f32x4 o4;
#pragma unroll
  for (int i = 0; i < 4; ++i) o4[i] = xv[i] + (a[i] - mean) * rs * g4[i] + b4[i];
  *reinterpret_cast<f32x4*>(yrow + tid * 4) = o4;
  // gate partial dots (fp32, from fp32 x2)
  float p0 = 0.f, p1 = 0.f, p2 = 0.f, p3 = 0.f;
#pragma unroll
  for (int i = 0; i < 4; ++i) {
    f32x4 w = *reinterpret_cast<const f32x4*>(Wg + (size_t)(tid * 4 + i) * 4);
    p0 += o4[i] * w[0]; p1 += o4[i] * w[1]; p2 += o4[i] * w[2]; p3 += o4[i] * w[3];
  }
#pragma unroll
  for (int o = 1; o < 64; o <<= 1) {
    p0 += __shfl_xor(p0, o); p1 += __shfl_xor(p1, o);
    p2 += __shfl_xor(p2, o); p3 += __shfl_xor(p3, o);
  }
  if (ln == 0) { gred[wv * 4] = p0; gred[wv * 4 + 1] = p1; gred[wv * 4 + 2] = p2; gred[wv * 4 + 3] = p3; }
  __syncthreads();
  if (tid == 0) {
    float lg[4];
#pragma unroll
    for (int c = 0; c < 4; ++c) lg[c] = gred[c] + gred[4 + c] + gred[8 + c] + gred[12 + c] + bg[c];
    int i0 = 0; float v0 = lg[0];
#pragma unroll
    for (int k = 1; k < 4; ++k) if (lg[k] > v0) { v0 = lg[k]; i0 = k; }
    int i1 = -1; float v1 = -3.4e38f;
#pragma unroll
    for (int k = 0; k < 4; ++k) if (k != i0 && lg[k] > v1) { v1 = lg[k]; i1 = k; }
    idx[row] = make_int2(i0, i1);
  }
  // pack bf16(x2): tid<128 -> expert A-pack granule tid; tid>=128 -> H-pack x-section
  int q = tid & 127;
  int kblk = q >> 3, kg = q & 7;
  int rrow = row & 255, mblk = row >> 8;
  const float* ys = yrow + q * 8;
  u16x8 o8;
#pragma unroll
  for (int j = 0; j < 8; ++j) o8[j] = f2bf(ys[j]);
  int pos = rrow * 8 + (kg ^ (rrow & 7));
  if (tid < 128) {
    *reinterpret_cast<u16x8*>(apack + (((size_t)mblk * 16 + kblk) * 2048 + pos) * 8) = o8;
  } else {
    *reinterpret_cast<u16x8*>(hpack + (((size_t)mblk * 48 + 32 + kblk) * 2048 + pos) * 8) = o8;
  }
}

__global__ __launch_bounds__(256) void final_ln_gelu(const float* __restrict__ fit, const float* __restrict__ bfit,
                                                     const float* __restrict__ g, const float* __restrict__ b,
                                                     float* __restrict__ out) {
  int row = blockIdx.x, tid = threadIdx.x;
  f32x4 hv = *reinterpret_cast<const f32x4*>(fit + (size_t)row * D_ + tid * 4);
  f32x4 bi = *reinterpret_cast<const f32x4*>(bfit + tid * 4);
  float a[4]; float s = 0.f, ss = 0.f;
#pragma unroll
  for (int i = 0; i < 4; ++i) { a[i] = hv[i] + bi[i]; s += a[i]; ss += a[i] * a[i]; }
#pragma unroll
  for (int o = 1; o < 64; o <<= 1) { s += __shfl_xor(s, o); ss += __shfl_xor(ss, o); }
  __shared__ float red[8];
  int wv = tid >> 6, ln = tid & 63;
  if (ln == 0) { red[wv] = s; red[4 + wv] = ss; }
  __syncthreads();
  float S = red[0] + red[1] + red[2] + red[3];
  float SS = red[4] + red[5] + red[6] + red[7];
  float mean = S * (1.f / 1024.f);
  float var = SS * (1.f / 1024.f) - mean * mean;
  float rs = rsqrtf(var + 1e-5f);
  f32x4 g4 = *reinterpret_cast<const f32x4*>(g + tid * 4);
  f32x4 b4 = *reinterpret_cast<const f32x4*>(b + tid * 4);
  f32x4 o4;
#pragma unroll
  for (int i = 0; i < 4; ++i) {
    float y = (a[i] - mean) * rs * g4[i] + b4[i];
    o4[i] = 0.5f * y * (1.f + erff(y * 0.70710678118654752f));
  }
  *reinterpret_cast<f32x4*>(out + (size_t)row * D_ + tid * 4) = o4;
}

// ============================================================================
// 8-wave 256x128 GEMM, BK=64, 3-stage LDS pipeline, counted vmcnt, setprio.
// MEMFOLD: 48-iter bf16x2 loop (ah*bh | ah*bl | al*bh), A/B stored hi|lo.
// EPI=0: C f32 [M][1024].  EPI=1: expert top-2 select -> swizzled H-pack bf16.
// ============================================================================
#define MFMA(a, b, c) __builtin_amdgcn_mfma_f32_16x16x32_bf16(a, b, c, 0, 0, 0)

template<int MEMFOLD, int EPI>
__global__ __launch_bounds__(512, 1) void gemm8(const u16* __restrict__ A, const u16* __restrict__ B,
                                                float* __restrict__ C, u16* __restrict__ hp,
                                                const int2* __restrict__ idx, const float* __restrict__ be,
                                                int KIT, int AKB, int BKB) {
  __shared__ __align__(16) u16 lds[3][24576];          // per stage: A[0,16384) B[16384,24576)
  const int tid = threadIdx.x;
  const int wid = tid >> 6, l = tid & 63;
  const int wm = wid >> 1, wn = wid & 1;
  const int lk = l >> 4, l15 = l & 15;
  const int bx = blockIdx.x, by = blockIdx.y, e = blockIdx.z;
  const int nblk = bx & 7;                             // XCD-pinned (dispatch id % 8 == bx % 8)
  const int mblk = (bx >> 3) | (by << 2);

  const u16* Ablob = A + (size_t)mblk * AKB * 16384;
  const u16* Bblob = B + ((size_t)e * 8 + nblk) * BKB * 8192;

  f32x4 acc[4][4];
#pragma unroll
  for (int i = 0; i < 4; ++i)
#pragma unroll
    for (int j = 0; j < 4; ++j) acc[i][j] = (f32x4){0.f, 0.f, 0.f, 0.f};

  auto stageA0 = [&](int s, int it) {                  // A rounds 0..2 (rows 0..191)
    int ablk = MEMFOLD ? (it < 16 ? it : it - 16) : it;
    const u16* As = Ablob + (size_t)ablk * 16384;
#pragma unroll
    for (int r = 0; r < 3; ++r) {
      int u = r * 512 + tid;
      gload16(As + (size_t)u * 8, &lds[s][u * 8]);
    }
  };
  auto stageA1B = [&](int s, int it) {                 // A round 3 + B rounds 0..1
    int ablk = MEMFOLD ? (it < 16 ? it : it - 16) : it;
    int bblk = MEMFOLD ? (it < 32 ? it : it - 32) : it;
    const u16* As = Ablob + (size_t)ablk * 16384;
    const u16* Bs = Bblob + (size_t)bblk * 8192;
    int u = 3 * 512 + tid;
    gload16(As + (size_t)u * 8, &lds[s][u * 8]);
#pragma unroll
    for (int r = 0; r < 2; ++r) {
      int v = r * 512 + tid;
      gload16(Bs + (size_t)v * 8, &lds[s][16384 + v * 8]);
    }
  };
  auto ldA = [&](int s, int mi, int ks) -> bf16x8 {
    int r = wm * 64 + mi * 16 + l15;
    int gp = (ks * 4 + lk) ^ (r & 7);
    return *reinterpret_cast<const bf16x8*>(&lds[s][(r * 8 + gp) * 8]);
  };
  auto ldB = [&](int s, int ni, int ks) -> bf16x8 {
    int c = wn * 64 + ni * 16 + l15;
    int gp = (ks * 4 + lk) ^ (c & 7);
    return *reinterpret_cast<const bf16x8*>(&lds[s][16384 + (c * 8 + gp) * 8]);
  };

  // prologue: 2 K-tiles in flight
  stageA0(0, 0); stageA1B(0, 0);
  stageA0(1, 1); stageA1B(1, 1);
  asm volatile("s_waitcnt vmcnt(6)" ::: "memory");
  asm volatile("s_barrier" ::: "memory");

  int cur = 0;
  for (int t = 0; t < KIT; ++t) {
    int nxt = cur + 2; if (nxt >= 3) nxt -= 3;
    bool pf = (t + 2) < KIT;
    bf16x8 A0, A1, A2, A3, B0, B1, B2, B3;
    // ---- phase 0 (ksub 0) ----
    A0 = ldA(cur, 0, 0); A1 = ldA(cur, 1, 0); A2 = ldA(cur, 2, 0); A3 = ldA(cur, 3, 0);
    B0 = ldB(cur, 0, 0); B1 = ldB(cur, 1, 0); B2 = ldB(cur, 2, 0); B3 = ldB(cur, 3, 0);
    if (pf) stageA0(nxt, t + 2);
    __builtin_amdgcn_s_setprio(1);
    acc[0][0] = MFMA(A0, B0, acc[0][0]); acc[1][0] = MFMA(A1, B0, acc[1][0]);
    acc[2][0] = MFMA(A2, B0, acc[2][0]); acc[3][0] = MFMA(A3, B0, acc[3][0]);
    acc[0][1] = MFMA(A0, B1, acc[0][1]); acc[1][1] = MFMA(A1, B1, acc[1][1]);
    acc[2][1] = MFMA(A2, B1, acc[2][1]); acc[3][1] = MFMA(A3, B1, acc[3][1]);
    acc[0][2] = MFMA(A0, B2, acc[0][2]); acc[1][2] = MFMA(A1, B2, acc[1][2]);
    acc[2][2] = MFMA(A2, B2, acc[2][2]); acc[3][2] = MFMA(A3, B2, acc[3][2]);
    acc[0][3] = MFMA(A0, B3, acc[0][3]); acc[1][3] = MFMA(A1, B3, acc[1][3]);
    acc[2][3] = MFMA(A2, B3, acc[2][3]); acc[3][3] = MFMA(A3, B3, acc[3][3]);
    __builtin_amdgcn_s_setprio(0);
    asm volatile("s_barrier" ::: "memory");
    // ---- phase 1 (ksub 1) ----
    A0 = ldA(cur, 0, 1); A1 = ldA(cur, 1, 1); A2 = ldA(cur, 2, 1); A3 = ldA(cur, 3, 1);
    B0 = ldB(cur, 0, 1); B1 = ldB(cur, 1, 1); B2 = ldB(cur, 2, 1); B3 = ldB(cur, 3, 1);
    if (pf) stageA1B(nxt, t + 2);
    __builtin_amdgcn_s_setprio(1);
    acc[0][0] = MFMA(A0, B0, acc[0][0]); acc[1][0] = MFMA(A1, B0, acc[1][0]);
    acc[2][0] = MFMA(A2, B0, acc[2][0]); acc[3][0] = MFMA(A3, B0, acc[3][0]);
    acc[0][1] = MFMA(A0, B1, acc[0][1]); acc[1][1] = MFMA(A1, B1, acc[1][1]);
    acc[2][1] = MFMA(A2, B1, acc[2][1]); acc[3][1] = MFMA(A3, B1, acc[3][1]);
    acc[0][2] = MFMA(A0, B2, acc[0][2]); acc[1][2] = MFMA(A1, B2, acc[1][2]);
    acc[2][2] = MFMA(A2, B2, acc[2][2]); acc[3][2] = MFMA(A3, B2, acc[3][2]);
    acc[0][3] = MFMA(A0, B3, acc[0][3]); acc[1][3] = MFMA(A1, B3, acc[1][3]);
    acc[2][3] = MFMA(A2, B3, acc[2][3]); acc[3][3] = MFMA(A3, B3, acc[3][3]);
    __builtin_amdgcn_s_setprio(0);
    if (pf) { asm volatile("s_waitcnt vmcnt(6)" ::: "memory"); }
    else    { asm volatile("s_waitcnt vmcnt(0)" ::: "memory"); }
    asm volatile("s_barrier" ::: "memory");
    cur += 1; if (cur >= 3) cur -= 3;
  }

  if (EPI == 0) {
#pragma unroll
    for (int mi = 0; mi < 4; ++mi) {
#pragma unroll
      for (int jj = 0; jj < 4; ++jj) {
        int row = mblk * 256 + wm * 64 + mi * 16 + lk * 4 + jj;
        float* Crow = C + (size_t)row * D_ + nblk * 128 + wn * 64 + l15;
#pragma unroll
        for (int ni = 0; ni < 4; ++ni) Crow[ni * 16] = acc[mi][ni][jj];
      }
    }
  } else {
#pragma unroll
    for (int mi = 0; mi < 4; ++mi) {
      int rbase = mblk * 256 + wm * 64 + mi * 16 + lk * 4;
      int2 rid[4];
#pragma unroll
      for (int jj = 0; jj < 4; ++jj) rid[jj] = idx[rbase + jj];
#pragma unroll
      for (int ni = 0; ni < 4; ++ni) {
        int col = nblk * 128 + wn * 64 + ni * 16 + l15;
        float bev = be[(size_t)e * D_ + col];
#pragma unroll
        for (int jj = 0; jj < 4; ++jj) {
          int slot = (rid[jj].x == e) ? 0 : ((rid[jj].y == e) ? 1 : -1);
          if (slot >= 0) {
            int row = rbase + jj;
            int rrow = row & 255;
            int kh = slot * D_ + col;
            int kblk = kh >> 6;
            int kg = (kh >> 3) & 7;
            size_t off = (((size_t)mblk * 48 + kblk) * 2048 + rrow * 8 + (kg ^ (rrow & 7))) * 8 + (kh & 7);
            hp[off] = f2bf(acc[mi][ni][jj] + bev);
          }
        }
      }
    }
  }
}

// ============================================================================
extern "C" void kernel_launch(void* const* d_in, const int* in_sizes, int n_in,
                              void* d_out, int out_size, void* d_ws, size_t ws_size,
                              hipStream_t stream) {
  const float* x_in = (const float*)d_in[0];
  const float* Wm   = (const float*)d_in[1];
  const float* bm   = (const float*)d_in[2];
  const float* ln_g = (const float*)d_in[3];
  const float* ln_b = (const float*)d_in[4];
  const float* Wg   = (const float*)d_in[5];
  const float* bg   = (const float*)d_in[6];
  const float* We   = (const float*)d_in[7];
  const float* be   = (const float*)d_in[8];
  const float* Wfit = (const float*)d_in[9];
  const float* bfit = (const float*)d_in[10];
  float* out = (float*)d_out;

  char* ws = (char*)d_ws;
  size_t off = 0;
  auto alloc = [&](size_t bytes) -> void* {
    void* p = ws + off; off += (bytes + 255) & ~(size_t)255; return p;
  };
  float* x1      = (float*)alloc((size_t)M_ * D_ * 4);              // 33.6 MB
  float* memb    = (float*)alloc((size_t)M_ * D_ * 4);              // 33.6 MB (mem, then fit)
  u16* AmemPack  = (u16*)alloc((size_t)32 * 32 * 2048 * 16);        // 33.6 MB
  u16* AplainPk  = (u16*)alloc((size_t)32 * 16 * 2048 * 16);        // 16.8 MB
  u16* Hpack     = (u16*)alloc((size_t)32 * 48 * 2048 * 16);        // 50.3 MB
  u16* WmPack    = (u16*)alloc((size_t)2 * 8 * 32 * 1024 * 16);     // 8.4 MB
  u16* WePack    = (u16*)alloc((size_t)4 * 8 * 16 * 1024 * 16);     // 8.4 MB
  u16* WfPack    = (u16*)alloc((size_t)8 * 48 * 1024 * 16);         // 6.3 MB
  int2* idxb     = (int2*)alloc((size_t)M_ * 8);                    // 64 KB

  // weight packs (LDS-tiled transposes)
  pack_W_mem  <<<256, 256, 0, stream>>>(Wm, WmPack);
  pack_W_plain<<<512, 256, 0, stream>>>(We, WePack, 16);
  pack_W_plain<<<384, 256, 0, stream>>>(Wfit, WfPack, 48);

  // memory layer 0
  pack_A_mem<<<8192, 256, 0, stream>>>(x_in, AmemPack);
  gemm8<1, 0><<<dim3(32, 8, 1), 512, 0, stream>>>(AmemPack, WmPack, memb, nullptr, nullptr, nullptr, 48, 32, 32);
  ln1_pack<<<8192, 256, 0, stream>>>(x_in, memb, bm, ln_g, ln_b, x1, AmemPack);
  // memory layer 1 (ln1 packed A already)
  gemm8<1, 0><<<dim3(32, 8, 1), 512, 0, stream>>>(AmemPack, WmPack + (size_t)2097152, memb,
                                                  nullptr, nullptr, nullptr, 48, 32, 32);
  // layer-2 LN + gate top-2 + expert A-pack + H-pack x-section
  ln2_gate_pack<<<8192, 256, 0, stream>>>(x1, memb, bm + D_, ln_g, ln_b, Wg, bg, AplainPk, Hpack, idxb);

  // experts: all 4, fused top-2 select -> swizzled H-pack link region (kblk 0..31)
  gemm8<0, 1><<<dim3(32, 8, 4), 512, 0, stream>>>(AplainPk, WePack, nullptr, Hpack, idxb, be, 16, 16, 16);

  // fit: [link | x2] @ Wfit
  gemm8<0, 0><<<dim3(32, 8, 1), 512, 0, stream>>>(Hpack, WfPack, memb, nullptr, nullptr, nullptr, 48, 48, 48);

  // final LN + exact GELU
  final_ln_gelu<<<8192, 256, 0, stream>>>(memb, bfit, ln_g, ln_b, out);
}

// Round 8
// 424.559 us; speedup vs baseline: 1.5650x; 1.1571x over previous
//
#include <hip/hip_runtime.h>
#include <hip/hip_bf16.h>
#include <math.h>

typedef __bf16 bf16x8 __attribute__((ext_vector_type(8)));
typedef float  f32x4  __attribute__((ext_vector_type(4)));
typedef unsigned int   u32;
typedef unsigned short u16;
typedef u16 u16x8 __attribute__((ext_vector_type(8)));

#define D_ 1024
#define M_ 8192

static __device__ __forceinline__ u16 f2bf(float f) {            // RNE float->bf16
  u32 x = __float_as_uint(f);
  return (u16)((x + 0x7fffu + ((x >> 16) & 1u)) >> 16);
}
static __device__ __forceinline__ float bf2f(u16 s) {
  union { u32 b; float f; } u; u.b = ((u32)s) << 16; return u.f;
}
static __device__ __forceinline__ void gload16(const u16* g, u16* l) {
  __builtin_amdgcn_global_load_lds((const __attribute__((address_space(1))) u32*)g,
                                   (__attribute__((address_space(3))) u32*)l, 16, 0, 0);
}

// ============================================================================
// Pack layouts (all 16B granules of 8 bf16, XOR-swizzled for conflict-free
// ds_read_b128):  A-blobs  [mblk][kblk64][2048 gran]  (256 rows x 8 kg)
//                 B-blobs  [e][nblk][kblk64][1024 gran](128 cols x 8 kg)
// granule slot (row, gp) holds data k-granule kg = gp ^ (row & 7).
// ============================================================================

// x (f32 [8192][1024]) -> bf16x2 A-pack [32 mblk][32 kblk][2048]  (hi: kblk<16, lo: >=16)
__global__ __launch_bounds__(256) void pack_A_mem(const float* __restrict__ x, u16* __restrict__ dst) {
  int gid = blockIdx.x * 256 + threadIdx.x;           // 2,097,152 granules
  int G = gid & 2047;
  int kblk = (gid >> 11) & 31;
  int mblk = gid >> 16;
  int rrow = G >> 3, gp = G & 7;
  int kg = gp ^ (rrow & 7);
  int region = kblk >> 4;                              // 0 hi, 1 lo
  int k = ((kblk & 15) * 8 + kg) * 8;
  const float* src = x + ((size_t)mblk * 256 + rrow) * D_ + k;
  f32x4 v0 = *reinterpret_cast<const f32x4*>(src);
  f32x4 v1 = *reinterpret_cast<const f32x4*>(src + 4);
  u16x8 o8;
#pragma unroll
  for (int j = 0; j < 4; ++j) {
    u16 h0 = f2bf(v0[j]); o8[j]     = region ? f2bf(v0[j] - bf2f(h0)) : h0;
    u16 h1 = f2bf(v1[j]); o8[4 + j] = region ? f2bf(v1[j] - bf2f(h1)) : h1;
  }
  *reinterpret_cast<u16x8*>(dst + (size_t)gid * 8) = o8;
}

// Wm f32 [2][1024][1024] -> WmPack [c][8 nblk][32 kblk][1024]  (hi kblk<16 | lo)
// grid 256 blocks (c*128 + kt*8 + nt), LDS-tiled transpose.
__global__ __launch_bounds__(256) void pack_W_mem(const float* __restrict__ W, u16* __restrict__ dst) {
  __shared__ float tile[64][129];
  int bidx = blockIdx.x;
  int nt = bidx & 7, kt = (bidx >> 3) & 15, c = bidx >> 7;
  const float* Ws = W + ((size_t)c * D_ + kt * 64) * D_ + nt * 128;
#pragma unroll
  for (int rep = 0; rep < 32; ++rep) {
    int idx = rep * 256 + threadIdx.x;
    tile[idx >> 7][idx & 127] = Ws[(size_t)(idx >> 7) * D_ + (idx & 127)];
  }
  __syncthreads();
#pragma unroll
  for (int rep = 0; rep < 8; ++rep) {
    int gi = rep * 256 + threadIdx.x;                  // 0..2047 (hi + lo)
    int region = gi >> 10;
    int G = gi & 1023;
    int col = G >> 3, gp = G & 7;
    int kg = gp ^ (col & 7);
    u16x8 o8;
#pragma unroll
    for (int j = 0; j < 8; ++j) {
      float v = tile[kg * 8 + j][col];
      u16 h = f2bf(v);
      o8[j] = region ? f2bf(v - bf2f(h)) : h;
    }
    int kblk = region * 16 + kt;
    size_t off = ((((size_t)c * 8 + nt) * 32 + kblk) * 1024 + col * 8 + gp) * 8;
    *reinterpret_cast<u16x8*>(dst + off) = o8;
  }
}

// W f32 (E slabs of [KBLK*64][1024]) -> [e][8 nblk][KBLK][1024], plain bf16.
// grid E*KBLK*8 blocks: b = (e*KBLK + kt)*8 + nt
__global__ __launch_bounds__(256) void pack_W_plain(const float* __restrict__ W, u16* __restrict__ dst, int KBLK) {
  __shared__ float tile[64][129];
  int bidx = blockIdx.x;
  int nt = bidx & 7;
  int t2 = bidx >> 3;
  int kt = t2 % KBLK;
  int e  = t2 / KBLK;
  const float* Ws = W + ((size_t)e * KBLK * 64 + kt * 64) * D_ + nt * 128;
#pragma unroll
  for (int rep = 0; rep < 32; ++rep) {
    int idx = rep * 256 + threadIdx.x;
    tile[idx >> 7][idx & 127] = Ws[(size_t)(idx >> 7) * D_ + (idx & 127)];
  }
  __syncthreads();
#pragma unroll
  for (int rep = 0; rep < 4; ++rep) {
    int gi = rep * 256 + threadIdx.x;                  // 0..1023
    int col = gi >> 3, gp = gi & 7;
    int kg = gp ^ (col & 7);
    u16x8 o8;
#pragma unroll
    for (int j = 0; j < 8; ++j) o8[j] = f2bf(tile[kg * 8 + j][col]);
    size_t off = ((((size_t)e * 8 + nt) * KBLK + kt) * 1024 + col * 8 + gp) * 8;
    *reinterpret_cast<u16x8*>(dst + off) = o8;
  }
}

// ============================================================================
// Fused LN kernels (1 row per 256-thread block)
// ============================================================================

// layer-1: x1 = x + LN(mem+bm); write x1 f32 AND bf16x2 A-pack for layer-2 GEMM
__global__ __launch_bounds__(256) void ln1_pack(const float* __restrict__ xin, const float* __restrict__ mem,
                                                const float* __restrict__ bm, const float* __restrict__ g,
                                                const float* __restrict__ b, float* __restrict__ xout,
                                                u16* __restrict__ apack) {
  int row = blockIdx.x, tid = threadIdx.x;
  __shared__ float yrow[1024];
  __shared__ float red[8];
  f32x4 mv = *reinterpret_cast<const f32x4*>(mem + (size_t)row * D_ + tid * 4);
  f32x4 bi = *reinterpret_cast<const f32x4*>(bm + tid * 4);
  float a[4]; float s = 0.f, ss = 0.f;
#pragma unroll
  for (int i = 0; i < 4; ++i) { a[i] = mv[i] + bi[i]; s += a[i]; ss += a[i] * a[i]; }
#pragma unroll
  for (int o = 1; o < 64; o <<= 1) { s += __shfl_xor(s, o); ss += __shfl_xor(ss, o); }
  int wv = tid >> 6, ln = tid & 63;
  if (ln == 0) { red[wv] = s; red[4 + wv] = ss; }
  __syncthreads();
  float S = red[0] + red[1] + red[2] + red[3];
  float SS = red[4] + red[5] + red[6] + red[7];
  float mean = S * (1.f / 1024.f);
  float var = SS * (1.f / 1024.f) - mean * mean;
  float rs = rsqrtf(var + 1e-5f);
  f32x4 g4 = *reinterpret_cast<const f32x4*>(g + tid * 4);
  f32x4 b4 = *reinterpret_cast<const f32x4*>(b + tid * 4);
  f32x4 xv = *reinterpret_cast<const f32x4*>(xin + (size_t)row * D_ + tid * 4);
  f32x4 o4;
#pragma unroll
  for (int i = 0; i < 4; ++i) o4[i] = xv[i] + (a[i] - mean) * rs * g4[i] + b4[i];
  *reinterpret_cast<f32x4*>(xout + (size_t)row * D_ + tid * 4) = o4;
  *reinterpret_cast<f32x4*>(yrow + tid * 4) = o4;
  __syncthreads();
  // pack: thread = one granule (hi for tid<128, lo else)
  int region = tid >> 7;
  int q = tid & 127;                                   // data granule 0..127
  int kblk = region * 16 + (q >> 3);
  int kg = q & 7;
  int rrow = row & 255, mblk = row >> 8;
  const float* ys = yrow + q * 8;
  u16x8 o8;
#pragma unroll
  for (int j = 0; j < 8; ++j) {
    float v = ys[j]; u16 h = f2bf(v);
    o8[j] = region ? f2bf(v - bf2f(h)) : h;
  }
  size_t off = (((size_t)mblk * 32 + kblk) * 2048 + rrow * 8 + (kg ^ (rrow & 7))) * 8;
  *reinterpret_cast<u16x8*>(apack + off) = o8;
}

// layer-2: x2 = x1 + LN(mem+bm1); fused gate top-2; write expert A-pack (plain bf16)
// and the x-section (kblk 32..47) of the fit H-pack.
__global__ __launch_bounds__(256) void ln2_gate_pack(const float* __restrict__ xin, const float* __restrict__ mem,
                                                     const float* __restrict__ bm1, const float* __restrict__ g,
                                                     const float* __restrict__ b, const float* __restrict__ Wg,
                                                     const float* __restrict__ bg, u16* __restrict__ apack,
                                                     u16* __restrict__ hpack, int2* __restrict__ idx) {
  int row = blockIdx.x, tid = threadIdx.x;
  __shared__ float yrow[1024];
  __shared__ float red[8];
  __shared__ float gred[16];
  f32x4 mv = *reinterpret_cast<const f32x4*>(mem + (size_t)row * D_ + tid * 4);
  f32x4 bi = *reinterpret_cast<const f32x4*>(bm1 + tid * 4);
  float a[4]; float s = 0.f, ss = 0.f;
#pragma unroll
  for (int i = 0; i < 4; ++i) { a[i] = mv[i] + bi[i]; s += a[i]; ss += a[i] * a[i]; }
#pragma unroll
  for (int o = 1; o < 64; o <<= 1) { s += __shfl_xor(s, o); ss += __shfl_xor(ss, o); }
  int wv = tid >> 6, ln = tid & 63;
  if (ln == 0) { red[wv] = s; red[4 + wv] = ss; }
  __syncthreads();
  float S = red[0] + red[1] + red[2] + red[3];
  float SS = red[4] + red[5] + red[6] + red[7];
  float mean = S * (1.f / 1024.f);
  float var = SS * (1.f / 1024.f) - mean * mean;
  float rs = rsqrtf(var + 1e-5f);
  f32x4 g4 = *reinterpret_cast<const f32x4*>(g + tid * 4);
  f32x4 b4 = *reinterpret_cast<const f32x4*>(b + tid * 4);
  f32x4 xv = *reinterpret_cast<const f32x4*>(xin + (size_t)row * D_ + tid * 4);
  f32x4 o4;
#pragma unroll
  for (int i = 0; i < 4; ++i) o4[i] = xv[i] + (a[i] - mean) * rs * g4[i] + b4[i];
  *reinterpret_cast<f32x4*>(yrow + tid * 4) = o4;
  // gate partial dots (fp32, from fp32 x2)
  float p0 = 0.f, p1 = 0.f, p2 = 0.f, p3 = 0.f;
#pragma unroll
  for (int i = 0; i < 4; ++i) {
    f32x4 w = *reinterpret_cast<const f32x4*>(Wg + (size_t)(tid * 4 + i) * 4);
    p0 += o4[i] * w[0]; p1 += o4[i] * w[1]; p2 += o4[i] * w[2]; p3 += o4[i] * w[3];
  }
#pragma unroll
  for (int o = 1; o < 64; o <<= 1) {
    p0 += __shfl_xor(p0, o); p1 += __shfl_xor(p1, o);
    p2 += __shfl_xor(p2, o); p3 += __shfl_xor(p3, o);
  }
  if (ln == 0) { gred[wv * 4] = p0; gred[wv * 4 + 1] = p1; gred[wv * 4 + 2] = p2; gred[wv * 4 + 3] = p3; }
  __syncthreads();
  if (tid == 0) {
    float lg[4];
#pragma unroll
    for (int c = 0; c < 4; ++c) lg[c] = gred[c] + gred[4 + c] + gred[8 + c] + gred[12 + c] + bg[c];
    int i0 = 0; float v0 = lg[0];
#pragma unroll
    for (int k = 1; k < 4; ++k) if (lg[k] > v0) { v0 = lg[k]; i0 = k; }
    int i1 = -1; float v1 = -3.4e38f;
#pragma unroll
    for (int k = 0; k < 4; ++k) if (k != i0 && lg[k] > v1) { v1 = lg[k]; i1 = k; }
    idx[row] = make_int2(i0, i1);
  }
  // pack bf16(x2): tid<128 -> expert A-pack granule tid; tid>=128 -> H-pack x-section
  int q = tid & 127;
  int kblk = q >> 3, kg = q & 7;
  int rrow = row & 255, mblk = row >> 8;
  const float* ys = yrow + q * 8;
  u16x8 o8;
#pragma unroll
  for (int j = 0; j < 8; ++j) o8[j] = f2bf(ys[j]);
  int pos = rrow * 8 + (kg ^ (rrow & 7));
  if (tid < 128) {
    *reinterpret_cast<u16x8*>(apack + (((size_t)mblk * 16 + kblk) * 2048 + pos) * 8) = o8;
  } else {
    *reinterpret_cast<u16x8*>(hpack + (((size_t)mblk * 48 + 32 + kblk) * 2048 + pos) * 8) = o8;
  }
}

__global__ __launch_bounds__(256) void final_ln_gelu(const float* __restrict__ fit, const float* __restrict__ bfit,
                                                     const float* __restrict__ g, const float* __restrict__ b,
                                                     float* __restrict__ out) {
  int row = blockIdx.x, tid = threadIdx.x;
  f32x4 hv = *reinterpret_cast<const f32x4*>(fit + (size_t)row * D_ + tid * 4);
  f32x4 bi = *reinterpret_cast<const f32x4*>(bfit + tid * 4);
  float a[4]; float s = 0.f, ss = 0.f;
#pragma unroll
  for (int i = 0; i < 4; ++i) { a[i] = hv[i] + bi[i]; s += a[i]; ss += a[i] * a[i]; }
#pragma unroll
  for (int o = 1; o < 64; o <<= 1) { s += __shfl_xor(s, o); ss += __shfl_xor(ss, o); }
  __shared__ float red[8];
  int wv = tid >> 6, ln = tid & 63;
  if (ln == 0) { red[wv] = s; red[4 + wv] = ss; }
  __syncthreads();
  float S = red[0] + red[1] + red[2] + red[3];
  float SS = red[4] + red[5] + red[6] + red[7];
  float mean = S * (1.f / 1024.f);
  float var = SS * (1.f / 1024.f) - mean * mean;
  float rs = rsqrtf(var + 1e-5f);
  f32x4 g4 = *reinterpret_cast<const f32x4*>(g + tid * 4);
  f32x4 b4 = *reinterpret_cast<const f32x4*>(b + tid * 4);
  f32x4 o4;
#pragma unroll
  for (int i = 0; i < 4; ++i) {
    float y = (a[i] - mean) * rs * g4[i] + b4[i];
    o4[i] = 0.5f * y * (1.f + erff(y * 0.70710678118654752f));
  }
  *reinterpret_cast<f32x4*>(out + (size_t)row * D_ + tid * 4) = o4;
}

// ============================================================================
// 8-wave 256x128 GEMM, BK=64, 3-stage LDS pipeline, counted vmcnt, setprio.
// Flat 1D grid, bid = e*256 + nblk*32 + mblk  ->  bid % 8 == mblk % 8, so all
// blocks sharing an A-slab land on ONE XCD (A served from its L2).
// MEMFOLD: 48-iter bf16x2 loop, kblk-major: per stored kblk the 3 subproducts
//   (ah*bh, ah*bl, al*bh) run adjacently -> L2 reuse distance 2-3 iters.
// EPI=0: C f32 [M][1024].  EPI=1: expert top-2 select -> swizzled H-pack bf16.
// ============================================================================
#define MFMA(a, b, c) __builtin_amdgcn_mfma_f32_16x16x32_bf16(a, b, c, 0, 0, 0)

template<int MEMFOLD, int EPI>
__global__ __launch_bounds__(512, 1) void gemm8(const u16* __restrict__ A, const u16* __restrict__ B,
                                                float* __restrict__ C, u16* __restrict__ hp,
                                                const int2* __restrict__ idx, const float* __restrict__ be,
                                                int KIT, int AKB, int BKB) {
  __shared__ __align__(16) u16 lds[3][24576];          // per stage: A[0,16384) B[16384,24576)
  const int tid = threadIdx.x;
  const int wid = tid >> 6, l = tid & 63;
  const int wm = wid >> 1, wn = wid & 1;
  const int lk = l >> 4, l15 = l & 15;
  const int bid = blockIdx.x;
  const int mblk = bid & 31;
  const int nblk = (bid >> 5) & 7;
  const int e    = bid >> 8;

  const u16* Ablob = A + (size_t)mblk * AKB * 16384;
  const u16* Bblob = B + ((size_t)e * 8 + nblk) * BKB * 8192;

  f32x4 acc[4][4];
#pragma unroll
  for (int i = 0; i < 4; ++i)
#pragma unroll
    for (int j = 0; j < 4; ++j) acc[i][j] = (f32x4){0.f, 0.f, 0.f, 0.f};

  // memfold iteration -> blob indices (kblk-major, 3 subproducts adjacent)
  auto amap = [&](int it) -> int {
    if (!MEMFOLD) return it;
    int kb = (int)((unsigned)it / 3u), sub = it - kb * 3;
    return kb + (sub == 2 ? 16 : 0);                   // sub 0,1: A-hi; sub 2: A-lo
  };
  auto bmap = [&](int it) -> int {
    if (!MEMFOLD) return it;
    int kb = (int)((unsigned)it / 3u), sub = it - kb * 3;
    return kb + (sub == 1 ? 16 : 0);                   // sub 0,2: B-hi; sub 1: B-lo
  };

  auto stageA0 = [&](int s, int it) {                  // A rounds 0..2 (rows 0..191)
    const u16* As = Ablob + (size_t)amap(it) * 16384;
#pragma unroll
    for (int r = 0; r < 3; ++r) {
      int u = r * 512 + tid;
      gload16(As + (size_t)u * 8, &lds[s][u * 8]);
    }
  };
  auto stageA1B = [&](int s, int it) {                 // A round 3 + B rounds 0..1
    const u16* As = Ablob + (size_t)amap(it) * 16384;
    const u16* Bs = Bblob + (size_t)bmap(it) * 8192;
    int u = 3 * 512 + tid;
    gload16(As + (size_t)u * 8, &lds[s][u * 8]);
#pragma unroll
    for (int r = 0; r < 2; ++r) {
      int v = r * 512 + tid;
      gload16(Bs + (size_t)v * 8, &lds[s][16384 + v * 8]);
    }
  };
  auto ldA = [&](int s, int mi, int ks) -> bf16x8 {
    int r = wm * 64 + mi * 16 + l15;
    int gp = (ks * 4 + lk) ^ (r & 7);
    return *reinterpret_cast<const bf16x8*>(&lds[s][(r * 8 + gp) * 8]);
  };
  auto ldB = [&](int s, int ni, int ks) -> bf16x8 {
    int c = wn * 64 + ni * 16 + l15;
    int gp = (ks * 4 + lk) ^ (c & 7);
    return *reinterpret_cast<const bf16x8*>(&lds[s][16384 + (c * 8 + gp) * 8]);
  };

  // prologue: 2 K-tiles in flight
  stageA0(0, 0); stageA1B(0, 0);
  stageA0(1, 1); stageA1B(1, 1);
  asm volatile("s_waitcnt vmcnt(6)" ::: "memory");
  asm volatile("s_barrier" ::: "memory");

  int cur = 0;
  for (int t = 0; t < KIT; ++t) {
    int nxt = cur + 2; if (nxt >= 3) nxt -= 3;
    bool pf = (t + 2) < KIT;
    bf16x8 A0, A1, A2, A3, B0, B1, B2, B3;
    // ---- phase 0 (ksub 0) ----
    A0 = ldA(cur, 0, 0); A1 = ldA(cur, 1, 0); A2 = ldA(cur, 2, 0); A3 = ldA(cur, 3, 0);
    B0 = ldB(cur, 0, 0); B1 = ldB(cur, 1, 0); B2 = ldB(cur, 2, 0); B3 = ldB(cur, 3, 0);
    if (pf) stageA0(nxt, t + 2);
    __builtin_amdgcn_s_setprio(1);
    acc[0][0] = MFMA(A0, B0, acc[0][0]); acc[1][0] = MFMA(A1, B0, acc[1][0]);
    acc[2][0] = MFMA(A2, B0, acc[2][0]); acc[3][0] = MFMA(A3, B0, acc[3][0]);
    acc[0][1] = MFMA(A0, B1, acc[0][1]); acc[1][1] = MFMA(A1, B1, acc[1][1]);
    acc[2][1] = MFMA(A2, B1, acc[2][1]); acc[3][1] = MFMA(A3, B1, acc[3][1]);
    acc[0][2] = MFMA(A0, B2, acc[0][2]); acc[1][2] = MFMA(A1, B2, acc[1][2]);
    acc[2][2] = MFMA(A2, B2, acc[2][2]); acc[3][2] = MFMA(A3, B2, acc[3][2]);
    acc[0][3] = MFMA(A0, B3, acc[0][3]); acc[1][3] = MFMA(A1, B3, acc[1][3]);
    acc[2][3] = MFMA(A2, B3, acc[2][3]); acc[3][3] = MFMA(A3, B3, acc[3][3]);
    __builtin_amdgcn_s_setprio(0);
    asm volatile("s_barrier" ::: "memory");
    // ---- phase 1 (ksub 1) ----
    A0 = ldA(cur, 0, 1); A1 = ldA(cur, 1, 1); A2 = ldA(cur, 2, 1); A3 = ldA(cur, 3, 1);
    B0 = ldB(cur, 0, 1); B1 = ldB(cur, 1, 1); B2 = ldB(cur, 2, 1); B3 = ldB(cur, 3, 1);
    if (pf) stageA1B(nxt, t + 2);
    __builtin_amdgcn_s_setprio(1);
    acc[0][0] = MFMA(A0, B0, acc[0][0]); acc[1][0] = MFMA(A1, B0, acc[1][0]);
    acc[2][0] = MFMA(A2, B0, acc[2][0]); acc[3][0] = MFMA(A3, B0, acc[3][0]);
    acc[0][1] = MFMA(A0, B1, acc[0][1]); acc[1][1] = MFMA(A1, B1, acc[1][1]);
    acc[2][1] = MFMA(A2, B1, acc[2][1]); acc[3][1] = MFMA(A3, B1, acc[3][1]);
    acc[0][2] = MFMA(A0, B2, acc[0][2]); acc[1][2] = MFMA(A1, B2, acc[1][2]);
    acc[2][2] = MFMA(A2, B2, acc[2][2]); acc[3][2] = MFMA(A3, B2, acc[3][2]);
    acc[0][3] = MFMA(A0, B3, acc[0][3]); acc[1][3] = MFMA(A1, B3, acc[1][3]);
    acc[2][3] = MFMA(A2, B3, acc[2][3]); acc[3][3] = MFMA(A3, B3, acc[3][3]);
    __builtin_amdgcn_s_setprio(0);
    if (pf) { asm volatile("s_waitcnt vmcnt(6)" ::: "memory"); }
    else    { asm volatile("s_waitcnt vmcnt(0)" ::: "memory"); }
    asm volatile("s_barrier" ::: "memory");
    cur += 1; if (cur >= 3) cur -= 3;
  }

  if (EPI == 0) {
#pragma unroll
    for (int mi = 0; mi < 4; ++mi) {
#pragma unroll
      for (int jj = 0; jj < 4; ++jj) {
        int row = mblk * 256 + wm * 64 + mi * 16 + lk * 4 + jj;
        float* Crow = C + (size_t)row * D_ + nblk * 128 + wn * 64 + l15;
#pragma unroll
        for (int ni = 0; ni < 4; ++ni) Crow[ni * 16] = acc[mi][ni][jj];
      }
    }
  } else {
#pragma unroll
    for (int mi = 0; mi < 4; ++mi) {
      int rbase = mblk * 256 + wm * 64 + mi * 16 + lk * 4;
      int2 rid[4];
#pragma unroll
      for (int jj = 0; jj < 4; ++jj) rid[jj] = idx[rbase + jj];
#pragma unroll
      for (int ni = 0; ni < 4; ++ni) {
        int col = nblk * 128 + wn * 64 + ni * 16 + l15;
        float bev = be[(size_t)e * D_ + col];
#pragma unroll
        for (int jj = 0; jj < 4; ++jj) {
          int slot = (rid[jj].x == e) ? 0 : ((rid[jj].y == e) ? 1 : -1);
          if (slot >= 0) {
            int row = rbase + jj;
            int rrow = row & 255;
            int kh = slot * D_ + col;
            int kblk = kh >> 6;
            int kg = (kh >> 3) & 7;
            size_t off = (((size_t)mblk * 48 + kblk) * 2048 + rrow * 8 + (kg ^ (rrow & 7))) * 8 + (kh & 7);
            hp[off] = f2bf(acc[mi][ni][jj] + bev);
          }
        }
      }
    }
  }
}

// ============================================================================
extern "C" void kernel_launch(void* const* d_in, const int* in_sizes, int n_in,
                              void* d_out, int out_size, void* d_ws, size_t ws_size,
                              hipStream_t stream) {
  const float* x_in = (const float*)d_in[0];
  const float* Wm   = (const float*)d_in[1];
  const float* bm   = (const float*)d_in[2];
  const float* ln_g = (const float*)d_in[3];
  const float* ln_b = (const float*)d_in[4];
  const float* Wg   = (const float*)d_in[5];
  const float* bg   = (const float*)d_in[6];
  const float* We   = (const float*)d_in[7];
  const float* be   = (const float*)d_in[8];
  const float* Wfit = (const float*)d_in[9];
  const float* bfit = (const float*)d_in[10];
  float* out = (float*)d_out;

  char* ws = (char*)d_ws;
  size_t off = 0;
  auto alloc = [&](size_t bytes) -> void* {
    void* p = ws + off; off += (bytes + 255) & ~(size_t)255; return p;
  };
  float* x1      = (float*)alloc((size_t)M_ * D_ * 4);              // 33.6 MB
  float* memb    = (float*)alloc((size_t)M_ * D_ * 4);              // 33.6 MB (mem, then fit)
  u16* AmemPack  = (u16*)alloc((size_t)32 * 32 * 2048 * 16);        // 33.6 MB
  u16* AplainPk  = (u16*)alloc((size_t)32 * 16 * 2048 * 16);        // 16.8 MB
  u16* Hpack     = (u16*)alloc((size_t)32 * 48 * 2048 * 16);        // 50.3 MB
  u16* WmPack    = (u16*)alloc((size_t)2 * 8 * 32 * 1024 * 16);     // 8.4 MB
  u16* WePack    = (u16*)alloc((size_t)4 * 8 * 16 * 1024 * 16);     // 8.4 MB
  u16* WfPack    = (u16*)alloc((size_t)8 * 48 * 1024 * 16);         // 6.3 MB
  int2* idxb     = (int2*)alloc((size_t)M_ * 8);                    // 64 KB

  // weight packs (LDS-tiled transposes)
  pack_W_mem  <<<256, 256, 0, stream>>>(Wm, WmPack);
  pack_W_plain<<<512, 256, 0, stream>>>(We, WePack, 16);
  pack_W_plain<<<384, 256, 0, stream>>>(Wfit, WfPack, 48);

  // memory layer 0
  pack_A_mem<<<8192, 256, 0, stream>>>(x_in, AmemPack);
  gemm8<1, 0><<<256, 512, 0, stream>>>(AmemPack, WmPack, memb, nullptr, nullptr, nullptr, 48, 32, 32);
  ln1_pack<<<8192, 256, 0, stream>>>(x_in, memb, bm, ln_g, ln_b, x1, AmemPack);
  // memory layer 1 (ln1 packed A already)
  gemm8<1, 0><<<256, 512, 0, stream>>>(AmemPack, WmPack + (size_t)2097152, memb,
                                       nullptr, nullptr, nullptr, 48, 32, 32);
  // layer-2 LN + gate top-2 + expert A-pack + H-pack x-section
  ln2_gate_pack<<<8192, 256, 0, stream>>>(x1, memb, bm + D_, ln_g, ln_b, Wg, bg, AplainPk, Hpack, idxb);

  // experts: all 4, fused top-2 select -> swizzled H-pack link region (kblk 0..31)
  gemm8<0, 1><<<1024, 512, 0, stream>>>(AplainPk, WePack, nullptr, Hpack, idxb, be, 16, 16, 16);

  // fit: [link | x2] @ Wfit
  gemm8<0, 0><<<256, 512, 0, stream>>>(Hpack, WfPack, memb, nullptr, nullptr, nullptr, 48, 48, 48);

  // final LN + exact GELU
  final_ln_gelu<<<8192, 256, 0, stream>>>(memb, bfit, ln_g, ln_b, out);
}